// Round 1
// 460.972 us; speedup vs baseline: 1.1814x; 1.1814x over previous
//
#include <hip/hip_runtime.h>
#include <stdint.h>

#define M_DIM 8192
#define K_DIM 4096
#define N_DIM 4096
#define QO 1024

// fast GEMM geometry: 256x256 tile, BK=64, 8 waves (2Mx4N), 128 KiB LDS dbuf
#define BM 256
#define BN 256
#define BK 64
#define NT (K_DIM / BK)     // 64
#define GX (N_DIM / BN)     // 16
#define GY (M_DIM / BM)     // 32
#define NWG (GX * GY)       // 512

// fallback tile
#define FBM 128
#define FBN 128
#define FBK 32

typedef __bf16 bf16x8_t __attribute__((ext_vector_type(8)));
typedef float f32x4_t __attribute__((ext_vector_type(4)));

__device__ __forceinline__ uint32_t f2bf_rne(float f) {
    union { float f; uint32_t u; } v; v.f = f;
    return (v.u + 0x7FFFu + ((v.u >> 16) & 1u)) >> 16;
}
__device__ __forceinline__ uint32_t pack2bf(float lo, float hi) {
    return f2bf_rne(lo) | (f2bf_rne(hi) << 16);
}

// ---- prep (merged): X fp32->bf16 and W_big build, one launch ----------------
#define NXB (M_DIM * K_DIM / 8 / 256)   // 16384 blocks for x
#define NWB (N_DIM * K_DIM / 8 / 256)   // 8192 blocks for w

__global__ __launch_bounds__(256) void prep_kernel(
    const float* __restrict__ x,
    const float* __restrict__ wrr, const float* __restrict__ wri,
    const float* __restrict__ wrj, const float* __restrict__ wrk,
    uint16_t* __restrict__ xb, uint16_t* __restrict__ wb)
{
    const int bid = blockIdx.x;
    if (bid < NXB) {
        const int i = bid * 256 + threadIdx.x;
        float4 v0 = ((const float4*)x)[2 * i];
        float4 v1 = ((const float4*)x)[2 * i + 1];
        uint4 o;
        o.x = pack2bf(v0.x, v0.y);
        o.y = pack2bf(v0.z, v0.w);
        o.z = pack2bf(v1.x, v1.y);
        o.w = pack2bf(v1.z, v1.w);
        ((uint4*)xb)[i] = o;
    } else {
        const int g = (bid - NXB) * 256 + threadIdx.x;
        const int n  = g >> 9;
        const int k8 = (g & 511) << 3;
        const int cp = n >> 10, o = n & 1023;
        const int c  = k8 >> 10, i = k8 & 1023;
        const int tsel = cp ^ c;
        const float* w = (tsel == 0) ? wrr : (tsel == 1) ? wri : (tsel == 2) ? wrj : wrk;
        const float s = ((0x428Eu >> ((cp << 2) | c)) & 1u) ? -1.0f : 1.0f;
        const float* p = w + (size_t)o * QO + i;
        float4 v0 = ((const float4*)p)[0];
        float4 v1 = ((const float4*)p)[1];
        uint4 ob;
        ob.x = pack2bf(s * v0.x, s * v0.y);
        ob.y = pack2bf(s * v0.z, s * v0.w);
        ob.z = pack2bf(s * v1.x, s * v1.y);
        ob.w = pack2bf(s * v1.z, s * v1.w);
        ((uint4*)wb)[g] = ob;
    }
}

// ---- 256x256 8-phase GEMM (T1 xcd-swizzle, T2 lds-swizzle, T3/T4 counted
//      vmcnt, T5 setprio). LDS: buf b at elem b*32768; A half h at +h*8192,
//      B at +16384 + h*8192. Half = 128 rows x 64 cols bf16, row = 128 B.
//      Swizzle: byte ^= ((row&7)<<4), applied inverse on global src (rule 21).

#define STAGE(bufEl, abEl, h, kb, G, RB) do {                                   \
    uint16_t* _d = sm + (bufEl) + (abEl) + (h) * 8192 + wid * 1024;             \
    const uint16_t* _g0 = (G) + (size_t)((RB) + (h) * 128 + sr0) * K_DIM + (kb) + sc0; \
    const uint16_t* _g1 = (G) + (size_t)((RB) + (h) * 128 + sr1) * K_DIM + (kb) + sc1; \
    __builtin_amdgcn_global_load_lds(                                           \
        (const __attribute__((address_space(1))) void*)_g0,                     \
        (__attribute__((address_space(3))) void*)_d, 16, 0, 0);                 \
    __builtin_amdgcn_global_load_lds(                                           \
        (const __attribute__((address_space(1))) void*)_g1,                     \
        (__attribute__((address_space(3))) void*)(_d + 512), 16, 0, 0);         \
} while (0)

#define LDA(mh) do {                                                            \
    const char* _b = sR + aBase + (mh) * 8192;                                  \
    _Pragma("unroll") for (int _m = 0; _m < 4; ++_m) {                          \
        af[_m][0] = *(const bf16x8_t*)(_b + _m * 2048 + ko0);                   \
        af[_m][1] = *(const bf16x8_t*)(_b + _m * 2048 + ko1);                   \
    }                                                                           \
} while (0)

#define LDB(nh) do {                                                            \
    const char* _b = sR + bBase;                                                \
    _Pragma("unroll") for (int _n = 0; _n < 2; ++_n) {                          \
        bfr[(nh) * 2 + _n][0] = *(const bf16x8_t*)(_b + ((nh) * 2 + _n) * 2048 + ko0); \
        bfr[(nh) * 2 + _n][1] = *(const bf16x8_t*)(_b + ((nh) * 2 + _n) * 2048 + ko1); \
    }                                                                           \
} while (0)

#define MM(mh, nh) do {                                                         \
    _Pragma("unroll") for (int _ks = 0; _ks < 2; ++_ks)                         \
    _Pragma("unroll") for (int _m = 0; _m < 4; ++_m)                            \
    _Pragma("unroll") for (int _n = 0; _n < 2; ++_n)                            \
        acc[(mh) * 4 + _m][(nh) * 2 + _n] =                                     \
            __builtin_amdgcn_mfma_f32_16x16x32_bf16(                            \
                af[_m][_ks], bfr[(nh) * 2 + _n][_ks],                           \
                acc[(mh) * 4 + _m][(nh) * 2 + _n], 0, 0, 0);                    \
} while (0)

#define FENCE() asm volatile("" ::: "memory")

#define PH(READS, STAGES, MFMAS, VM) do {                                       \
    READS;                                                                      \
    STAGES;                                                                     \
    FENCE();                                                                    \
    __builtin_amdgcn_s_barrier();                                               \
    asm volatile("s_waitcnt lgkmcnt(0)" ::: "memory");                          \
    __builtin_amdgcn_s_setprio(1);                                              \
    MFMAS;                                                                      \
    __builtin_amdgcn_s_setprio(0);                                              \
    VM;                                                                         \
    FENCE();                                                                    \
    __builtin_amdgcn_s_barrier();                                               \
    FENCE();                                                                    \
} while (0)

__global__ __launch_bounds__(512, 2) void qgemm8p_kernel(
    const uint16_t* __restrict__ Abf, const uint16_t* __restrict__ Bbf,
    const float* __restrict__ bias, float* __restrict__ C)
{
    __shared__ __align__(16) uint16_t sm[65536];   // 128 KiB

    const int tid  = threadIdx.x;
    const int wid  = tid >> 6;
    const int lane = tid & 63;
    const int wm = wid >> 2, wn = wid & 3;         // 2x4 waves, wave tile 128x64

    // XCD-aware bijective swizzle (NWG=512, %8==0)
    const int flat = blockIdx.x;
    const int swb  = ((flat & 7) << 6) | (flat >> 3);
    const int bm = swb >> 4, bn = swb & 15;
    const int aRow = bm * BM, bRow = bn * BN;

    // staging coords: LDS byte o = wid*2048 + i*1024 + lane*16 (linear dest);
    // global src pre-swizzled: lin = o ^ ((row(o)&7)<<4), row(o)&7 = lane>>3
    const int o0   = wid * 2048 + lane * 16;
    const int swzS = ((lane >> 3) & 7) << 4;
    const int lin0 = o0 ^ swzS;
    const int sr0 = lin0 >> 7, sc0 = (lin0 & 127) >> 1;
    const int sr1 = sr0 + 8,   sc1 = sc0;          // i=1: +1024 B = +8 rows

    // fragment read coords (byte offsets within a half, swizzled)
    const int fr  = lane & 15;
    const int q16 = ((lane >> 4) & 3) << 4;
    const int ko0 = q16 ^ ((fr & 7) << 4);
    const int ko1 = ko0 ^ 64;                      // ks=1: +64 B
    const int aBase = wm * 16384 + fr * 128;
    const int bBase = 32768 + (wn >> 1) * 16384 + (wn & 1) * 8192 + fr * 128;
    const char* const smc = (const char*)sm;

    f32x4_t acc[8][4];
#pragma unroll
    for (int a = 0; a < 8; ++a)
#pragma unroll
        for (int b = 0; b < 4; ++b)
            acc[a][b] = (f32x4_t){0.f, 0.f, 0.f, 0.f};

    bf16x8_t af[4][2];    // current A half (one mh at a time)
    bf16x8_t bfr[4][2];   // all B frags of the tile

    // prologue: B0_0,B1_0,A0_0,A1_0 -> buf0; B0_1,B1_1 -> buf1; tile0 landed
    STAGE(0,     16384, 0, 0,  Bbf, bRow);
    STAGE(0,     16384, 1, 0,  Bbf, bRow);
    STAGE(0,     0,     0, 0,  Abf, aRow);
    STAGE(0,     0,     1, 0,  Abf, aRow);
    STAGE(32768, 16384, 0, BK, Bbf, bRow);
    STAGE(32768, 16384, 1, BK, Bbf, bRow);
    asm volatile("s_waitcnt vmcnt(4)" ::: "memory");
    __builtin_amdgcn_s_barrier();
    FENCE();

    int bufR = 0;   // element base of tile t's buffer
#pragma unroll 1
    for (int t = 0; t < NT - 2; ++t) {
        const int bufW = 32768 - bufR;
        const char* sR = smc + bufR * 2;
        const int kb1 = (t + 1) * BK;
        const int kb2 = (t + 2) * BK;
        // p0: A-lo + B-lo reads; stage A0_{t+1} (other buf; its A dead since t-1.p2)
        PH(LDA(0); LDB(0), STAGE(bufW, 0, 0, kb1, Abf, aRow), MM(0, 0), (void)0);
        // p1: B-hi reads; stage A1_{t+1}
        PH(LDB(1),         STAGE(bufW, 0, 1, kb1, Abf, aRow), MM(0, 1), (void)0);
        // p2: A-hi reads (A of tile t now dead); stage B0_{t+2} into this buf (B dead after p1)
        PH(LDA(1),         STAGE(bufR, 16384, 0, kb2, Bbf, bRow), MM(1, 1), (void)0);
        // p3: no reads; stage B1_{t+2}; counted vmcnt(4) covers all of tile t+1,
        //     leaves B0/B1_{t+2} (4 loads) in flight
        PH((void)0,        STAGE(bufR, 16384, 1, kb2, Bbf, bRow), MM(1, 0),
           asm volatile("s_waitcnt vmcnt(4)" ::: "memory"));
        bufR = bufW;
    }
    {   // t = NT-2: stage only A halves of last tile, then drain
        const int bufW = 32768 - bufR;
        const char* sR = smc + bufR * 2;
        const int kb1 = (NT - 1) * BK;
        PH(LDA(0); LDB(0), STAGE(bufW, 0, 0, kb1, Abf, aRow), MM(0, 0), (void)0);
        PH(LDB(1),         STAGE(bufW, 0, 1, kb1, Abf, aRow), MM(0, 1), (void)0);
        PH(LDA(1),         (void)0,                           MM(1, 1), (void)0);
        PH((void)0,        (void)0,                           MM(1, 0),
           asm volatile("s_waitcnt vmcnt(0)" ::: "memory"));
        bufR = bufW;
    }
    {   // t = NT-1: compute only
        const char* sR = smc + bufR * 2;
        PH(LDA(0); LDB(0), (void)0, MM(0, 0), (void)0);
        PH(LDB(1),         (void)0, MM(0, 1), (void)0);
        PH(LDA(1),         (void)0, MM(1, 1), (void)0);
        PH((void)0,        (void)0, MM(1, 0), (void)0);
    }

    // epilogue: C/D layout col=lane&15, row=(lane>>4)*4+reg
    const int row0 = bm * BM + wm * 128 + ((lane >> 4) << 2);
    const int col0 = bn * BN + wn * 64 + (lane & 15);
#pragma unroll
    for (int ni = 0; ni < 4; ++ni) {
        const int col = col0 + ni * 16;
        const float bv = bias[col & (QO - 1)];
#pragma unroll
        for (int mi = 0; mi < 8; ++mi) {
            float* cptr = C + (size_t)(row0 + mi * 16) * N_DIM + col;
#pragma unroll
            for (int rr = 0; rr < 4; ++rr)
                cptr[(size_t)rr * N_DIM] = acc[mi][ni][rr] + bv;
        }
    }
}

// ---- fallback GEMM (no ws): fp32 inputs, on-the-fly bf16 convert ------------
__global__ __launch_bounds__(256) void qgemm_fb_kernel(
    const float* __restrict__ x,
    const float* __restrict__ wrr, const float* __restrict__ wri,
    const float* __restrict__ wrj, const float* __restrict__ wrk,
    const float* __restrict__ bias, float* __restrict__ C)
{
    __shared__ uint16_t lA[FBM * FBK];
    __shared__ uint16_t lB[FBN * FBK];
    const int t    = threadIdx.x;
    const int wave = t >> 6;
    const int lane = t & 63;
    const int bn = blockIdx.x, bm = blockIdx.y;
    const int wm = wave >> 1, wn = wave & 1;

    f32x4_t acc[4][4];
#pragma unroll
    for (int a = 0; a < 4; ++a)
#pragma unroll
        for (int b = 0; b < 4; ++b)
            acc[a][b] = (f32x4_t){0.f, 0.f, 0.f, 0.f};

    const int fr  = lane & 15;
    const int fkb = (lane >> 4) << 3;
    const uint16_t* pA[4];
    const uint16_t* pB[4];
#pragma unroll
    for (int i = 0; i < 4; ++i) {
        pA[i] = lA + (wm * 64 + i * 16 + fr) * FBK + fkb;
        pB[i] = lB + (wn * 64 + i * 16 + fr) * FBK + fkb;
    }

    const int mr = t >> 1;
    const int mc = (t & 1) << 4;
    int ng = bn * FBN + mr;
    int bcp = ng >> 10;
    int bo  = ng & 1023;

#pragma unroll 1
    for (int kb = 0; kb < K_DIM; kb += FBK) {
        const float* pa = x + (size_t)(bm * FBM + mr) * K_DIM + kb + mc;
        float4 a0 = ((const float4*)pa)[0], a1 = ((const float4*)pa)[1],
               a2 = ((const float4*)pa)[2], a3 = ((const float4*)pa)[3];
        uint4 wv0 = make_uint4(pack2bf(a0.x, a0.y), pack2bf(a0.z, a0.w),
                               pack2bf(a1.x, a1.y), pack2bf(a1.z, a1.w));
        uint4 wv1 = make_uint4(pack2bf(a2.x, a2.y), pack2bf(a2.z, a2.w),
                               pack2bf(a3.x, a3.y), pack2bf(a3.z, a3.w));
        *(uint4*)(lA + mr * FBK + mc)     = wv0;
        *(uint4*)(lA + mr * FBK + mc + 8) = wv1;

        int k0 = kb + mc;
        int c  = k0 >> 10, ii = k0 & 1023;
        int tsel = bcp ^ c;
        const float* w = (tsel == 0) ? wrr : (tsel == 1) ? wri : (tsel == 2) ? wrj : wrk;
        float s = ((0x428Eu >> ((bcp << 2) | c)) & 1u) ? -1.0f : 1.0f;
        const float* pb = w + (size_t)bo * QO + ii;
        float4 b0 = ((const float4*)pb)[0], b1 = ((const float4*)pb)[1],
               b2 = ((const float4*)pb)[2], b3 = ((const float4*)pb)[3];
        uint4 u0 = make_uint4(pack2bf(s * b0.x, s * b0.y), pack2bf(s * b0.z, s * b0.w),
                              pack2bf(s * b1.x, s * b1.y), pack2bf(s * b1.z, s * b1.w));
        uint4 u1 = make_uint4(pack2bf(s * b2.x, s * b2.y), pack2bf(s * b2.z, s * b2.w),
                              pack2bf(s * b3.x, s * b3.y), pack2bf(s * b3.z, s * b3.w));
        *(uint4*)(lB + mr * FBK + mc)     = u0;
        *(uint4*)(lB + mr * FBK + mc + 8) = u1;
        __syncthreads();

        bf16x8_t afr[4], bfrg[4];
#pragma unroll
        for (int i = 0; i < 4; ++i) {
            afr[i]  = *(const bf16x8_t*)pA[i];
            bfrg[i] = *(const bf16x8_t*)pB[i];
        }
#pragma unroll
        for (int mi = 0; mi < 4; ++mi)
#pragma unroll
            for (int ni = 0; ni < 4; ++ni)
                acc[mi][ni] = __builtin_amdgcn_mfma_f32_16x16x32_bf16(
                    afr[mi], bfrg[ni], acc[mi][ni], 0, 0, 0);
        __syncthreads();
    }

    const int row0 = bm * FBM + wm * 64 + ((lane >> 4) << 2);
    const int col0 = bn * FBN + wn * 64 + (lane & 15);
#pragma unroll
    for (int ni = 0; ni < 4; ++ni) {
        const int col = col0 + ni * 16;
        const float bv = bias[col & (QO - 1)];
#pragma unroll
        for (int mi = 0; mi < 4; ++mi) {
            const int r = row0 + mi * 16;
            float* cptr = C + (size_t)r * N_DIM + col;
#pragma unroll
            for (int rr = 0; rr < 4; ++rr)
                cptr[(size_t)rr * N_DIM] = acc[mi][ni][rr] + bv;
        }
    }
}

extern "C" void kernel_launch(void* const* d_in, const int* in_sizes, int n_in,
                              void* d_out, int out_size, void* d_ws, size_t ws_size,
                              hipStream_t stream) {
    const float* x   = (const float*)d_in[0];
    const float* wrr = (const float*)d_in[1];
    const float* wri = (const float*)d_in[2];
    const float* wrj = (const float*)d_in[3];
    const float* wrk = (const float*)d_in[4];
    const float* brr = (const float*)d_in[5];
    float* out = (float*)d_out;

    const size_t xb_bytes = (size_t)M_DIM * K_DIM * 2;   // 64 MiB
    const size_t wb_bytes = (size_t)N_DIM * K_DIM * 2;   // 32 MiB

    if (ws_size >= xb_bytes + wb_bytes) {
        uint16_t* xb = (uint16_t*)d_ws;
        uint16_t* wb = (uint16_t*)((char*)d_ws + xb_bytes);
        prep_kernel<<<NXB + NWB, 256, 0, stream>>>(x, wrr, wri, wrj, wrk, xb, wb);
        qgemm8p_kernel<<<dim3(NWG), dim3(512), 0, stream>>>(xb, wb, brr, out);
    } else {
        dim3 grid(N_DIM / FBN, M_DIM / FBM);
        qgemm_fb_kernel<<<grid, 256, 0, stream>>>(x, wrr, wri, wrj, wrk, brr, out);
    }
}

// Round 3
// 449.869 us; speedup vs baseline: 1.2105x; 1.0247x over previous
//
#include <hip/hip_runtime.h>
#include <stdint.h>

#define M_DIM 8192
#define K_DIM 4096
#define N_DIM 4096
#define QO 1024

// fast GEMM geometry: 256x256 tile, BK=64, 8 waves (2Mx4N), 128 KiB LDS dbuf
#define BM 256
#define BN 256
#define BK 64
#define NT (K_DIM / BK)     // 64
#define GX (N_DIM / BN)     // 16
#define GY (M_DIM / BM)     // 32
#define NWG (GX * GY)       // 512

// fallback tile
#define FBM 128
#define FBN 128
#define FBK 32

typedef __bf16 bf16x8_t __attribute__((ext_vector_type(8)));
typedef float f32x4_t __attribute__((ext_vector_type(4)));

__device__ __forceinline__ uint32_t f2bf_rne(float f) {
    union { float f; uint32_t u; } v; v.f = f;
    return (v.u + 0x7FFFu + ((v.u >> 16) & 1u)) >> 16;
}
__device__ __forceinline__ uint32_t pack2bf(float lo, float hi) {
    return f2bf_rne(lo) | (f2bf_rne(hi) << 16);
}

// ---- prep (merged): X fp32->bf16 and W_big build, one launch ----------------
#define NXB (M_DIM * K_DIM / 8 / 256)   // 16384 blocks for x
#define NWB (N_DIM * K_DIM / 8 / 256)   // 8192 blocks for w

__global__ __launch_bounds__(256) void prep_kernel(
    const float* __restrict__ x,
    const float* __restrict__ wrr, const float* __restrict__ wri,
    const float* __restrict__ wrj, const float* __restrict__ wrk,
    uint16_t* __restrict__ xb, uint16_t* __restrict__ wb)
{
    const int bid = blockIdx.x;
    if (bid < NXB) {
        const int i = bid * 256 + threadIdx.x;
        float4 v0 = ((const float4*)x)[2 * i];
        float4 v1 = ((const float4*)x)[2 * i + 1];
        uint4 o;
        o.x = pack2bf(v0.x, v0.y);
        o.y = pack2bf(v0.z, v0.w);
        o.z = pack2bf(v1.x, v1.y);
        o.w = pack2bf(v1.z, v1.w);
        ((uint4*)xb)[i] = o;
    } else {
        const int g = (bid - NXB) * 256 + threadIdx.x;
        const int n  = g >> 9;
        const int k8 = (g & 511) << 3;
        const int cp = n >> 10, o = n & 1023;
        const int c  = k8 >> 10, i = k8 & 1023;
        const int tsel = cp ^ c;
        const float* w = (tsel == 0) ? wrr : (tsel == 1) ? wri : (tsel == 2) ? wrj : wrk;
        const float s = ((0x428Eu >> ((cp << 2) | c)) & 1u) ? -1.0f : 1.0f;
        const float* p = w + (size_t)o * QO + i;
        float4 v0 = ((const float4*)p)[0];
        float4 v1 = ((const float4*)p)[1];
        uint4 ob;
        ob.x = pack2bf(s * v0.x, s * v0.y);
        ob.y = pack2bf(s * v0.z, s * v0.w);
        ob.z = pack2bf(s * v1.x, s * v1.y);
        ob.w = pack2bf(s * v1.z, s * v1.w);
        ((uint4*)wb)[g] = ob;
    }
}

// ---- 256x256 8-phase GEMM (T1 xcd-swizzle, T2 lds-swizzle, T3/T4 counted
//      vmcnt, T5 setprio). LDS: buf b at elem b*32768; A half h at +h*8192,
//      B at +16384 + h*8192. Half = 128 rows x 64 cols bf16, row = 128 B.
//      Swizzle: byte ^= ((row&7)<<4), applied inverse on global src (rule 21).
//      K-loop unrolled x2 so both LDS buffer bases are compile-time constants.
//
//      LIVENESS NOTE (round-2 lesson): staged half h = M-rows [h*128,(h+1)*128),
//      and wm=1 / wn>=2 waves read half-1 already at p0. So ALL four staged
//      pieces of tile t+1 must retire before tile t+1's p0 -> the deepest legal
//      wait is a single vmcnt(4) at p3 (leaves only B(t+2) in flight).

#define STAGEA(bufEl, h, kb) do {                                               \
    uint16_t* _d = sm + (bufEl) + (h) * 8192 + wid * 1024;                      \
    __builtin_amdgcn_global_load_lds(                                           \
        (const __attribute__((address_space(1))) void*)(gAs0 + (size_t)(h) * 128 * K_DIM + (kb)), \
        (__attribute__((address_space(3))) void*)_d, 16, 0, 0);                 \
    __builtin_amdgcn_global_load_lds(                                           \
        (const __attribute__((address_space(1))) void*)(gAs1 + (size_t)(h) * 128 * K_DIM + (kb)), \
        (__attribute__((address_space(3))) void*)(_d + 512), 16, 0, 0);         \
} while (0)

#define STAGEB(bufEl, h, kb) do {                                               \
    uint16_t* _d = sm + (bufEl) + 16384 + (h) * 8192 + wid * 1024;              \
    __builtin_amdgcn_global_load_lds(                                           \
        (const __attribute__((address_space(1))) void*)(gBs0 + (size_t)(h) * 128 * K_DIM + (kb)), \
        (__attribute__((address_space(3))) void*)_d, 16, 0, 0);                 \
    __builtin_amdgcn_global_load_lds(                                           \
        (const __attribute__((address_space(1))) void*)(gBs1 + (size_t)(h) * 128 * K_DIM + (kb)), \
        (__attribute__((address_space(3))) void*)(_d + 512), 16, 0, 0);         \
} while (0)

#define LDA(mh) do {                                                            \
    const char* _b = sR + aBase + (mh) * 8192;                                  \
    _Pragma("unroll") for (int _m = 0; _m < 4; ++_m) {                          \
        af[_m][0] = *(const bf16x8_t*)(_b + _m * 2048 + ko0);                   \
        af[_m][1] = *(const bf16x8_t*)(_b + _m * 2048 + ko1);                   \
    }                                                                           \
} while (0)

#define LDB(nh) do {                                                            \
    const char* _b = sR + bBase;                                                \
    _Pragma("unroll") for (int _n = 0; _n < 2; ++_n) {                          \
        bfr[(nh) * 2 + _n][0] = *(const bf16x8_t*)(_b + ((nh) * 2 + _n) * 2048 + ko0); \
        bfr[(nh) * 2 + _n][1] = *(const bf16x8_t*)(_b + ((nh) * 2 + _n) * 2048 + ko1); \
    }                                                                           \
} while (0)

#define MM(mh, nh) do {                                                         \
    _Pragma("unroll") for (int _ks = 0; _ks < 2; ++_ks)                         \
    _Pragma("unroll") for (int _m = 0; _m < 4; ++_m)                            \
    _Pragma("unroll") for (int _n = 0; _n < 2; ++_n)                            \
        acc[(mh) * 4 + _m][(nh) * 2 + _n] =                                     \
            __builtin_amdgcn_mfma_f32_16x16x32_bf16(                            \
                af[_m][_ks], bfr[(nh) * 2 + _n][_ks],                           \
                acc[(mh) * 4 + _m][(nh) * 2 + _n], 0, 0, 0);                    \
} while (0)

#define FENCE() asm volatile("" ::: "memory")
#define VM4 asm volatile("s_waitcnt vmcnt(4)" ::: "memory")
#define VM0 asm volatile("s_waitcnt vmcnt(0)" ::: "memory")

#define PH(READS, STAGES, MFMAS, VM) do {                                       \
    READS;                                                                      \
    STAGES;                                                                     \
    FENCE();                                                                    \
    __builtin_amdgcn_s_barrier();                                               \
    asm volatile("s_waitcnt lgkmcnt(0)" ::: "memory");                          \
    __builtin_amdgcn_s_setprio(1);                                              \
    MFMAS;                                                                      \
    __builtin_amdgcn_s_setprio(0);                                              \
    VM;                                                                         \
    FENCE();                                                                    \
    __builtin_amdgcn_s_barrier();                                               \
    FENCE();                                                                    \
} while (0)

// One K-tile. BR/BW: element base of read/write LDS buffer (compile-time).
// t1/t2: K-tile indices whose halves are staged (A of t1, B of t2).
// Ledger (per wave, oldest first) entering p0: {B0(t+1),B1(t+1)} = 4.
//   p0 +A0(t+1)=6 | p1 +A1(t+1)=8 | p2 +B0(t+2)=10 | p3 +B1(t+2)=12,
//   VM4 leaves {B0(t+2),B1(t+2)} -> all of tile t+1 landed before its p0.
#define TILE_MAIN(BR, BW, t1, t2) do {                                          \
    const char* sR = smc + (size_t)(BR) * 2;                                    \
    PH(LDA(0); LDB(0), STAGEA(BW, 0, (t1) * BK), MM(0, 0), (void)0);            \
    PH(LDB(1),         STAGEA(BW, 1, (t1) * BK), MM(0, 1), (void)0);            \
    PH(LDA(1),         STAGEB(BR, 0, (t2) * BK), MM(1, 1), (void)0);            \
    PH((void)0,        STAGEB(BR, 1, (t2) * BK), MM(1, 0), VM4);                \
} while (0)

__global__ __launch_bounds__(512, 2) void qgemm8p_kernel(
    const uint16_t* __restrict__ Abf, const uint16_t* __restrict__ Bbf,
    const float* __restrict__ bias, float* __restrict__ C)
{
    __shared__ __align__(16) uint16_t sm[65536];   // 128 KiB

    const int tid  = threadIdx.x;
    const int wid  = tid >> 6;
    const int lane = tid & 63;
    const int wm = wid >> 2, wn = wid & 3;         // 2x4 waves, wave tile 128x64

    // XCD-aware bijective swizzle (NWG=512, %8==0)
    const int flat = blockIdx.x;
    const int swb  = ((flat & 7) << 6) | (flat >> 3);
    const int bm = swb >> 4, bn = swb & 15;
    const int aRow = bm * BM, bRow = bn * BN;

    // staging coords: LDS byte o = wid*2048 + i*1024 + lane*16 (linear dest);
    // global src pre-swizzled: lin = o ^ ((row(o)&7)<<4), row(o)&7 = lane>>3
    const int o0   = wid * 2048 + lane * 16;
    const int swzS = ((lane >> 3) & 7) << 4;
    const int lin0 = o0 ^ swzS;
    const int sr0 = lin0 >> 7, sc0 = (lin0 & 127) >> 1;
    const int sr1 = sr0 + 8,   sc1 = sc0;          // i=1: +1024 B = +8 rows

    // per-thread loop-invariant global staging bases
    const uint16_t* gAs0 = Abf + (size_t)(aRow + sr0) * K_DIM + sc0;
    const uint16_t* gAs1 = Abf + (size_t)(aRow + sr1) * K_DIM + sc1;
    const uint16_t* gBs0 = Bbf + (size_t)(bRow + sr0) * K_DIM + sc0;
    const uint16_t* gBs1 = Bbf + (size_t)(bRow + sr1) * K_DIM + sc1;

    // fragment read coords (byte offsets within a half, swizzled)
    const int fr  = lane & 15;
    const int q16 = ((lane >> 4) & 3) << 4;
    const int ko0 = q16 ^ ((fr & 7) << 4);
    const int ko1 = ko0 ^ 64;                      // ks=1: +64 B
    const int aBase = wm * 16384 + fr * 128;
    const int bBase = 32768 + (wn >> 1) * 16384 + (wn & 1) * 8192 + fr * 128;
    const char* const smc = (const char*)sm;

    f32x4_t acc[8][4];
#pragma unroll
    for (int a = 0; a < 8; ++a)
#pragma unroll
        for (int b = 0; b < 4; ++b)
            acc[a][b] = (f32x4_t){0.f, 0.f, 0.f, 0.f};

    bf16x8_t af[4][2];    // current A half (one mh at a time)
    bf16x8_t bfr[4][2];   // all B frags of the tile

    // prologue: B0_0,B1_0,A0_0,A1_0 -> buf0; B0_1,B1_1 -> buf1.
    // vmcnt(4) retires ALL of tile 0 -> in flight: {B0(1),B1(1)} (invariant)
    STAGEB(0,     0, 0);
    STAGEB(0,     1, 0);
    STAGEA(0,     0, 0);
    STAGEA(0,     1, 0);
    STAGEB(32768, 0, BK);
    STAGEB(32768, 1, BK);
    VM4;
    __builtin_amdgcn_s_barrier();
    FENCE();

    // main loop: x2 unrolled, static LDS bases. even tile -> buf0, odd -> buf1
#pragma unroll 1
    for (int t = 0; t < NT - 2; t += 2) {
        TILE_MAIN(0,     32768, t + 1, t + 2);
        TILE_MAIN(32768, 0,     t + 2, t + 3);
    }
    {   // tile NT-2 (buf0): stage A of last tile only, then full drain
        const char* sR = smc;
        PH(LDA(0); LDB(0), STAGEA(32768, 0, (NT - 1) * BK), MM(0, 0), (void)0);
        PH(LDB(1),         STAGEA(32768, 1, (NT - 1) * BK), MM(0, 1), (void)0);
        PH(LDA(1),         (void)0,                         MM(1, 1), (void)0);
        PH((void)0,        (void)0,                         MM(1, 0), VM0);
    }
    {   // tile NT-1 (buf1): compute only, everything landed
        const char* sR = smc + 65536;
        PH(LDA(0); LDB(0), (void)0, MM(0, 0), (void)0);
        PH(LDB(1),         (void)0, MM(0, 1), (void)0);
        PH(LDA(1),         (void)0, MM(1, 1), (void)0);
        PH((void)0,        (void)0, MM(1, 0), (void)0);
    }

    // epilogue: C/D layout col=lane&15, row=(lane>>4)*4+reg
    const int row0 = bm * BM + wm * 128 + ((lane >> 4) << 2);
    const int col0 = bn * BN + wn * 64 + (lane & 15);
#pragma unroll
    for (int ni = 0; ni < 4; ++ni) {
        const int col = col0 + ni * 16;
        const float bv = bias[col & (QO - 1)];
#pragma unroll
        for (int mi = 0; mi < 8; ++mi) {
            float* cptr = C + (size_t)(row0 + mi * 16) * N_DIM + col;
#pragma unroll
            for (int rr = 0; rr < 4; ++rr)
                cptr[(size_t)rr * N_DIM] = acc[mi][ni][rr] + bv;
        }
    }
}

// ---- fallback GEMM (no ws): fp32 inputs, on-the-fly bf16 convert ------------
__global__ __launch_bounds__(256) void qgemm_fb_kernel(
    const float* __restrict__ x,
    const float* __restrict__ wrr, const float* __restrict__ wri,
    const float* __restrict__ wrj, const float* __restrict__ wrk,
    const float* __restrict__ bias, float* __restrict__ C)
{
    __shared__ uint16_t lA[FBM * FBK];
    __shared__ uint16_t lB[FBN * FBK];
    const int t    = threadIdx.x;
    const int wave = t >> 6;
    const int lane = t & 63;
    const int bn = blockIdx.x, bm = blockIdx.y;
    const int wm = wave >> 1, wn = wave & 1;

    f32x4_t acc[4][4];
#pragma unroll
    for (int a = 0; a < 4; ++a)
#pragma unroll
        for (int b = 0; b < 4; ++b)
            acc[a][b] = (f32x4_t){0.f, 0.f, 0.f, 0.f};

    const int fr  = lane & 15;
    const int fkb = (lane >> 4) << 3;
    const uint16_t* pA[4];
    const uint16_t* pB[4];
#pragma unroll
    for (int i = 0; i < 4; ++i) {
        pA[i] = lA + (wm * 64 + i * 16 + fr) * FBK + fkb;
        pB[i] = lB + (wn * 64 + i * 16 + fr) * FBK + fkb;
    }

    const int mr = t >> 1;
    const int mc = (t & 1) << 4;
    int ng = bn * FBN + mr;
    int bcp = ng >> 10;
    int bo  = ng & 1023;

#pragma unroll 1
    for (int kb = 0; kb < K_DIM; kb += FBK) {
        const float* pa = x + (size_t)(bm * FBM + mr) * K_DIM + kb + mc;
        float4 a0 = ((const float4*)pa)[0], a1 = ((const float4*)pa)[1],
               a2 = ((const float4*)pa)[2], a3 = ((const float4*)pa)[3];
        uint4 wv0 = make_uint4(pack2bf(a0.x, a0.y), pack2bf(a0.z, a0.w),
                               pack2bf(a1.x, a1.y), pack2bf(a1.z, a1.w));
        uint4 wv1 = make_uint4(pack2bf(a2.x, a2.y), pack2bf(a2.z, a2.w),
                               pack2bf(a3.x, a3.y), pack2bf(a3.z, a3.w));
        *(uint4*)(lA + mr * FBK + mc)     = wv0;
        *(uint4*)(lA + mr * FBK + mc + 8) = wv1;

        int k0 = kb + mc;
        int c  = k0 >> 10, ii = k0 & 1023;
        int tsel = bcp ^ c;
        const float* w = (tsel == 0) ? wrr : (tsel == 1) ? wri : (tsel == 2) ? wrj : wrk;
        float s = ((0x428Eu >> ((bcp << 2) | c)) & 1u) ? -1.0f : 1.0f;
        const float* pb = w + (size_t)bo * QO + ii;
        float4 b0 = ((const float4*)pb)[0], b1 = ((const float4*)pb)[1],
               b2 = ((const float4*)pb)[2], b3 = ((const float4*)pb)[3];
        uint4 u0 = make_uint4(pack2bf(s * b0.x, s * b0.y), pack2bf(s * b0.z, s * b0.w),
                              pack2bf(s * b1.x, s * b1.y), pack2bf(s * b1.z, s * b1.w));
        uint4 u1 = make_uint4(pack2bf(s * b2.x, s * b2.y), pack2bf(s * b2.z, s * b2.w),
                              pack2bf(s * b3.x, s * b3.y), pack2bf(s * b3.z, s * b3.w));
        *(uint4*)(lB + mr * FBK + mc)     = u0;
        *(uint4*)(lB + mr * FBK + mc + 8) = u1;
        __syncthreads();

        bf16x8_t afr[4], bfrg[4];
#pragma unroll
        for (int i = 0; i < 4; ++i) {
            afr[i]  = *(const bf16x8_t*)pA[i];
            bfrg[i] = *(const bf16x8_t*)pB[i];
        }
#pragma unroll
        for (int mi = 0; mi < 4; ++mi)
#pragma unroll
            for (int ni = 0; ni < 4; ++ni)
                acc[mi][ni] = __builtin_amdgcn_mfma_f32_16x16x32_bf16(
                    afr[mi], bfrg[ni], acc[mi][ni], 0, 0, 0);
        __syncthreads();
    }

    const int row0 = bm * FBM + wm * 64 + ((lane >> 4) << 2);
    const int col0 = bn * FBN + wn * 64 + (lane & 15);
#pragma unroll
    for (int ni = 0; ni < 4; ++ni) {
        const int col = col0 + ni * 16;
        const float bv = bias[col & (QO - 1)];
#pragma unroll
        for (int mi = 0; mi < 4; ++mi) {
            const int r = row0 + mi * 16;
            float* cptr = C + (size_t)r * N_DIM + col;
#pragma unroll
            for (int rr = 0; rr < 4; ++rr)
                cptr[(size_t)rr * N_DIM] = acc[mi][ni][rr] + bv;
        }
    }
}

extern "C" void kernel_launch(void* const* d_in, const int* in_sizes, int n_in,
                              void* d_out, int out_size, void* d_ws, size_t ws_size,
                              hipStream_t stream) {
    const float* x   = (const float*)d_in[0];
    const float* wrr = (const float*)d_in[1];
    const float* wri = (const float*)d_in[2];
    const float* wrj = (const float*)d_in[3];
    const float* wrk = (const float*)d_in[4];
    const float* brr = (const float*)d_in[5];
    float* out = (float*)d_out;

    const size_t xb_bytes = (size_t)M_DIM * K_DIM * 2;   // 64 MiB
    const size_t wb_bytes = (size_t)N_DIM * K_DIM * 2;   // 32 MiB

    if (ws_size >= xb_bytes + wb_bytes) {
        uint16_t* xb = (uint16_t*)d_ws;
        uint16_t* wb = (uint16_t*)((char*)d_ws + xb_bytes);
        prep_kernel<<<NXB + NWB, 256, 0, stream>>>(x, wrr, wri, wrj, wrk, xb, wb);
        qgemm8p_kernel<<<dim3(NWG), dim3(512), 0, stream>>>(xb, wb, brr, out);
    } else {
        dim3 grid(N_DIM / FBN, M_DIM / FBM);
        qgemm_fb_kernel<<<grid, 256, 0, stream>>>(x, wrr, wri, wrj, wrk, brr, out);
    }
}